// Round 5
// baseline (17.318 us; speedup 1.0000x reference)
//
#include <hip/hip_runtime.h>
#include <hip/hip_bf16.h>

constexpr int HS = 4;   // hedge slots
constexpr int NS = 64;  // neighbor samples == wavefront size
constexpr int T  = 32;  // n_types == output dim
constexpr int E  = 64;  // node embedding width
constexpr int RPB = 4;  // rows per block

// 512 threads = 8 waves per block; 4 rows per block (grid = B/4 = 1024).
// Gather: wave w owns row (w>>1), slot pair {2*(w&1), 2*(w&1)+1} -> 2
// independent chains in flight. Epilogue: even wave -> score path, odd
// wave -> embedding path, for row (w>>1). 4 blocks/CU x 8 waves = full
// 32-wave residency in a single batch.
__global__ __launch_bounds__(512)
void polyhype_kernel(const int*   __restrict__ neighbors,      // [B, HS]
                     const int*   __restrict__ train_hedges,   // [B]
                     const int*   __restrict__ labels,         // [B]
                     const int*   __restrict__ neighborhedges, // [N_NODES, NS]
                     const int*   __restrict__ hedgetypes,     // [N_HEDGES]
                     const int*   __restrict__ nodeEmb,        // [N_NODES, E]
                     const float* __restrict__ tf,             // [T, T]
                     const float* __restrict__ W1,             // [T, T]
                     const float* __restrict__ b1,             // [T]
                     const float* __restrict__ W2,             // [E, T]
                     const float* __restrict__ b2,             // [T]
                     float*       __restrict__ out,            // scores|sig|emb
                     int B)
{
    const int wid  = threadIdx.x >> 6;
    const int lane = threadIdx.x & 63;
    const int t    = lane & 31;
    const int b0   = blockIdx.x * RPB;

    const int r     = wid >> 1;          // row this wave serves (gather + epilogue)
    const int br    = b0 + r;
    const int spair = wid & 1;           // slot pair {0,1} or {2,3}
    const int s0    = spair * 2;
    const int s1    = s0 + 1;

    __shared__ float aggp[RPB][HS][T];   // per-row per-slot masked-mean type vec
    __shared__ float embp[RPB][HS][E];   // per-row per-slot nodeEmb row

    const int th = train_hedges[br];
    const int2 nn = ((const int2*)(neighbors + br * HS))[spair];  // 2 adjacent slots
    const int n0 = nn.x, n1 = nn.y;

    // --- both gather chains issued back-to-back (ILP=2) ---
    const int e0 = neighborhedges[(size_t)n0 * NS + lane];
    const int e1 = neighborhedges[(size_t)n1 * NS + lane];
    const int t0 = hedgetypes[e0];
    const int t1 = hedgetypes[e1];
    embp[r][s0][lane] = (float)nodeEmb[(size_t)n0 * E + lane];
    embp[r][s1][lane] = (float)nodeEmb[(size_t)n1 * E + lane];

    const unsigned long long mm0 = __ballot(e0 != th);
    const unsigned long long mm1 = __ballot(e1 != th);
    const float rd0 = 1.0f / fmaxf((float)__popcll(mm0), 1.0f);
    const float rd1 = 1.0f / fmaxf((float)__popcll(mm1), 1.0f);

    // --- ballot histogram for both slots; tf element shared per k ---
    float a0 = 0.f, a1 = 0.f;
    #pragma unroll
    for (int k = 0; k < T; ++k) {
        const float w  = tf[k * T + t];
        const float c0 = (float)__popcll(__ballot(t0 == k) & mm0);
        const float c1 = (float)__popcll(__ballot(t1 == k) & mm1);
        a0 += c0 * w;
        a1 += c1 * w;
    }
    if (lane < T) {
        aggp[r][s0][t] = a0 * rd0;
        aggp[r][s1][t] = a1 * rd1;
    }

    __syncthreads();

    float* scores = out;
    float* sig    = out + (size_t)B * T;
    float* emb    = out + (size_t)2 * B * T;

    if ((wid & 1) == 0) {
        // scores path for row r
        if (lane < T) {
            float agg = (aggp[r][0][t] + aggp[r][1][t] + aggp[r][2][t] + aggp[r][3][t]) * 0.25f
                      + tf[labels[br] * T + t];
            aggp[r][0][t] = agg;   // stage for matvec broadcast
        }
        __builtin_amdgcn_wave_barrier();
        if (lane < T) {
            float v = b1[t];
            #pragma unroll 8
            for (int u = 0; u < T; ++u)
                v += aggp[r][0][u] * W1[u * T + t];
            scores[br * T + t] = v;
            sig[br * T + t]    = 1.0f / (1.0f + __expf(-v));
            emb[(size_t)br * 2 * T + t] = v;
        }
    } else {
        // embedding path for row r
        const float em = (embp[r][0][lane] + embp[r][1][lane] +
                          embp[r][2][lane] + embp[r][3][lane]) * 0.25f;
        embp[r][0][lane] = em;
        __builtin_amdgcn_wave_barrier();
        if (lane < T) {
            float v = b2[t];
            #pragma unroll 8
            for (int e = 0; e < E; ++e)
                v += embp[r][0][e] * W2[e * T + t];
            emb[(size_t)br * 2 * T + T + t] = v;
        }
    }
}

extern "C" void kernel_launch(void* const* d_in, const int* in_sizes, int n_in,
                              void* d_out, int out_size, void* d_ws, size_t ws_size,
                              hipStream_t stream) {
    const int*   neighbors      = (const int*)  d_in[0];
    const int*   train_hedges   = (const int*)  d_in[1];
    const int*   labels         = (const int*)  d_in[2];
    const int*   neighborhedges = (const int*)  d_in[3];
    const int*   hedgetypes     = (const int*)  d_in[4];
    const int*   nodeEmb        = (const int*)  d_in[5];
    const float* tf             = (const float*)d_in[6];
    const float* W1             = (const float*)d_in[7];
    const float* b1             = (const float*)d_in[8];
    const float* W2             = (const float*)d_in[9];
    const float* b2             = (const float*)d_in[10];
    float*       out            = (float*)      d_out;

    const int B = in_sizes[1];   // train_hedges is [B]

    const int grid = (B + RPB - 1) / RPB;
    polyhype_kernel<<<grid, 512, 0, stream>>>(
        neighbors, train_hedges, labels, neighborhedges, hedgetypes, nodeEmb,
        tf, W1, b1, W2, b2, out, B);
}